// Round 1
// baseline (202.126 us; speedup 1.0000x reference)
//
#include <hip/hip_runtime.h>

// Problem constants (from reference): B=32, S=3, T=1000, F=257
#define BATCH   32
#define NSRC    3
#define TF      257000            // T*F
#define N4      (TF / 4)          // 64250 float4 groups per (b,s) slice
#define CHUNKS  64                // blocks per batch element
#define THREADS 256

// Kernel 1: pairwise partial sums.
// pw[b*9 + j*3 + k] accumulates sum_{t,f} |pred[b,j,t,f] - tgt[b,k,t,f]|
__global__ __launch_bounds__(THREADS) void pairwise_kernel(
    const float* __restrict__ pred,
    const float* __restrict__ tgt,
    float* __restrict__ pw)
{
    const int b     = blockIdx.x / CHUNKS;
    const int chunk = blockIdx.x % CHUNKS;

    const float4* pr[NSRC];
    const float4* tg[NSRC];
#pragma unroll
    for (int s = 0; s < NSRC; ++s) {
        pr[s] = reinterpret_cast<const float4*>(pred + (size_t)(b * NSRC + s) * TF);
        tg[s] = reinterpret_cast<const float4*>(tgt  + (size_t)(b * NSRC + s) * TF);
    }

    float acc[NSRC][NSRC];
#pragma unroll
    for (int j = 0; j < NSRC; ++j)
#pragma unroll
        for (int k = 0; k < NSRC; ++k) acc[j][k] = 0.0f;

    for (int i = chunk * THREADS + threadIdx.x; i < N4; i += CHUNKS * THREADS) {
        float4 a[NSRC], t[NSRC];
#pragma unroll
        for (int s = 0; s < NSRC; ++s) { a[s] = pr[s][i]; t[s] = tg[s][i]; }
#pragma unroll
        for (int j = 0; j < NSRC; ++j) {
#pragma unroll
            for (int k = 0; k < NSRC; ++k) {
                acc[j][k] += fabsf(a[j].x - t[k].x)
                           + fabsf(a[j].y - t[k].y)
                           + fabsf(a[j].z - t[k].z)
                           + fabsf(a[j].w - t[k].w);
            }
        }
    }

    // Wave (64-lane) shuffle reduction, then one atomic per wave per pair.
#pragma unroll
    for (int j = 0; j < NSRC; ++j) {
#pragma unroll
        for (int k = 0; k < NSRC; ++k) {
            float v = acc[j][k];
#pragma unroll
            for (int off = 32; off > 0; off >>= 1) v += __shfl_down(v, off);
            if ((threadIdx.x & 63) == 0) atomicAdd(&pw[b * 9 + j * 3 + k], v);
        }
    }
}

// Kernel 2: per-batch 6-permutation min/argmin + global mean.
// out[0] = mean_b min_loss[b]; out[1 + b*3 + s] = (float)best_perm[b][s]
__global__ __launch_bounds__(64) void finalize_kernel(
    const float* __restrict__ pw,
    float* __restrict__ out)
{
    const int b = threadIdx.x;
    float minv = 0.0f;

    if (b < BATCH) {
        float m[NSRC][NSRC];
#pragma unroll
        for (int j = 0; j < NSRC; ++j)
#pragma unroll
            for (int k = 0; k < NSRC; ++k)
                m[j][k] = pw[b * 9 + j * 3 + k] * (1.0f / (float)TF);

        const int perms[6][3] = {
            {0,1,2},{0,2,1},{1,0,2},{1,2,0},{2,0,1},{2,1,0}
        };

        float best = 3.402823e38f;
        int   bi   = 0;
#pragma unroll
        for (int p = 0; p < 6; ++p) {
            float l = (m[perms[p][0]][0] + m[perms[p][1]][1] + m[perms[p][2]][2])
                      * (1.0f / 3.0f);
            if (l < best) { best = l; bi = p; }   // first-occurrence argmin
        }

        out[1 + b * 3 + 0] = (float)perms[bi][0];
        out[1 + b * 3 + 1] = (float)perms[bi][1];
        out[1 + b * 3 + 2] = (float)perms[bi][2];
        minv = best;
    }

    // sum across the 64-lane wave (lanes >= BATCH contribute 0)
#pragma unroll
    for (int off = 32; off > 0; off >>= 1) minv += __shfl_down(minv, off);
    if (threadIdx.x == 0) out[0] = minv * (1.0f / (float)BATCH);
}

extern "C" void kernel_launch(void* const* d_in, const int* in_sizes, int n_in,
                              void* d_out, int out_size, void* d_ws, size_t ws_size,
                              hipStream_t stream)
{
    const float* pred = (const float*)d_in[0];
    const float* tgt  = (const float*)d_in[1];
    float* out = (float*)d_out;
    float* pw  = (float*)d_ws;

    // ws is NOT re-poisoned/zeroed between replays — zero our accumulators.
    hipMemsetAsync(pw, 0, BATCH * 9 * sizeof(float), stream);

    pairwise_kernel<<<BATCH * CHUNKS, THREADS, 0, stream>>>(pred, tgt, pw);
    finalize_kernel<<<1, 64, 0, stream>>>(pw, out);
}

// Round 2
// 43.632 us; speedup vs baseline: 4.6325x; 4.6325x over previous
//
#include <hip/hip_runtime.h>

// Problem constants (from reference): B=32, S=3, T=1000, F=257
#define BATCH   32
#define NSRC    3
#define TF      257000            // T*F
#define N4      (TF / 4)          // 64250 float4 groups per (b,s) slice
#define CHUNKS  64                // blocks per batch element
#define THREADS 256
#define STRIDE  (CHUNKS * THREADS)   // 16384

// Kernel 1: per-block pairwise partial sums (NO global atomics — they were
// the R1 bottleneck: 73k contended fp atomics on 18 cache lines ~= 200us).
// partial[block*9 + j*3 + k] = this block's sum of |pred[b,j]-tgt[b,k]|
__global__ __launch_bounds__(THREADS) void pairwise_kernel(
    const float* __restrict__ pred,
    const float* __restrict__ tgt,
    float* __restrict__ partial)
{
    const int b     = blockIdx.x / CHUNKS;
    const int chunk = blockIdx.x % CHUNKS;

    const float4* pr[NSRC];
    const float4* tg[NSRC];
#pragma unroll
    for (int s = 0; s < NSRC; ++s) {
        pr[s] = reinterpret_cast<const float4*>(pred + (size_t)(b * NSRC + s) * TF);
        tg[s] = reinterpret_cast<const float4*>(tgt  + (size_t)(b * NSRC + s) * TF);
    }

    const int start = chunk * THREADS + threadIdx.x;   // in [0, 16384)

    float acc[NSRC][NSRC];
#pragma unroll
    for (int j = 0; j < NSRC; ++j)
#pragma unroll
        for (int k = 0; k < NSRC; ++k) acc[j][k] = 0.0f;

    // 3 guaranteed strided iterations: issue all 18 loads up-front (MLP),
    // then consume. start + 2*16384 = max 49151 < 64250 always.
    float4 A[3][NSRC], T[3][NSRC];
#pragma unroll
    for (int u = 0; u < 3; ++u) {
        const int i = start + u * STRIDE;
#pragma unroll
        for (int s = 0; s < NSRC; ++s) { A[u][s] = pr[s][i]; T[u][s] = tg[s][i]; }
    }
#pragma unroll
    for (int u = 0; u < 3; ++u) {
#pragma unroll
        for (int j = 0; j < NSRC; ++j)
#pragma unroll
            for (int k = 0; k < NSRC; ++k) {
                acc[j][k] += fabsf(A[u][j].x - T[u][k].x)
                           + fabsf(A[u][j].y - T[u][k].y)
                           + fabsf(A[u][j].z - T[u][k].z)
                           + fabsf(A[u][j].w - T[u][k].w);
            }
    }

    // Conditional 4th iteration (start < 64250 - 49152 = 15098).
    const int i3 = start + 3 * STRIDE;
    if (i3 < N4) {
        float4 a[NSRC], t[NSRC];
#pragma unroll
        for (int s = 0; s < NSRC; ++s) { a[s] = pr[s][i3]; t[s] = tg[s][i3]; }
#pragma unroll
        for (int j = 0; j < NSRC; ++j)
#pragma unroll
            for (int k = 0; k < NSRC; ++k) {
                acc[j][k] += fabsf(a[j].x - t[k].x)
                           + fabsf(a[j].y - t[k].y)
                           + fabsf(a[j].z - t[k].z)
                           + fabsf(a[j].w - t[k].w);
            }
    }

    // Wave-level shuffle reduce, then LDS across the 4 waves, then ONE
    // 9-float store per block to this block's private workspace slot.
    __shared__ float red[THREADS / 64][9];
    const int wave = threadIdx.x >> 6;
    const int lane = threadIdx.x & 63;

#pragma unroll
    for (int j = 0; j < NSRC; ++j)
#pragma unroll
        for (int k = 0; k < NSRC; ++k) {
            float v = acc[j][k];
#pragma unroll
            for (int off = 32; off > 0; off >>= 1) v += __shfl_down(v, off);
            if (lane == 0) red[wave][j * 3 + k] = v;
        }
    __syncthreads();

    if (threadIdx.x < 9) {
        float v = red[0][threadIdx.x] + red[1][threadIdx.x]
                + red[2][threadIdx.x] + red[3][threadIdx.x];
        partial[(size_t)blockIdx.x * 9 + threadIdx.x] = v;
    }
}

// Kernel 2: reduce the 2048x9 partials, per-batch 6-perm argmin, mean.
// out[0] = mean_b min_loss[b]; out[1 + b*3 + s] = (float)best_perm[b][s]
__global__ __launch_bounds__(320) void finalize_kernel(
    const float* __restrict__ partial,
    float* __restrict__ out)
{
    __shared__ float m[BATCH][9];
    const int g = threadIdx.x;

    if (g < BATCH * 9) {
        const int b = g / 9;
        const int p = g % 9;
        float s = 0.0f;
#pragma unroll 8
        for (int c = 0; c < CHUNKS; ++c)
            s += partial[(size_t)(b * CHUNKS + c) * 9 + p];
        m[b][p] = s * (1.0f / (float)TF);
    }
    __syncthreads();

    if (threadIdx.x < 64) {
        float minv = 0.0f;
        if (threadIdx.x < BATCH) {
            const int b = threadIdx.x;
            const int perms[6][3] = {
                {0,1,2},{0,2,1},{1,0,2},{1,2,0},{2,0,1},{2,1,0}
            };
            float best = 3.402823e38f;
            int   bi   = 0;
#pragma unroll
            for (int p = 0; p < 6; ++p) {
                float l = (m[b][perms[p][0] * 3 + 0]
                         + m[b][perms[p][1] * 3 + 1]
                         + m[b][perms[p][2] * 3 + 2]) * (1.0f / 3.0f);
                if (l < best) { best = l; bi = p; }   // first-occurrence argmin
            }
            out[1 + b * 3 + 0] = (float)perms[bi][0];
            out[1 + b * 3 + 1] = (float)perms[bi][1];
            out[1 + b * 3 + 2] = (float)perms[bi][2];
            minv = best;
        }
#pragma unroll
        for (int off = 32; off > 0; off >>= 1) minv += __shfl_down(minv, off);
        if (threadIdx.x == 0) out[0] = minv * (1.0f / (float)BATCH);
    }
}

extern "C" void kernel_launch(void* const* d_in, const int* in_sizes, int n_in,
                              void* d_out, int out_size, void* d_ws, size_t ws_size,
                              hipStream_t stream)
{
    const float* pred = (const float*)d_in[0];
    const float* tgt  = (const float*)d_in[1];
    float* out     = (float*)d_out;
    float* partial = (float*)d_ws;   // 2048 * 9 floats = 73728 B, fully
                                     // rewritten every call (no zeroing needed)

    pairwise_kernel<<<BATCH * CHUNKS, THREADS, 0, stream>>>(pred, tgt, partial);
    finalize_kernel<<<1, 320, 0, stream>>>(partial, out);
}